// Round 9
// baseline (477.221 us; speedup 1.0000x reference)
//
#include <hip/hip_runtime.h>

#define SPATIAL 110592   // 48*48*48
#define CH 160
#define CPAD 168         // W row pad (336B stride, 16B aligned)
#define NTOT (CH*SPATIAL)
#define WELEM (CH*CPAD)  // 26880 ushort per weight matrix
#define EPSV 1e-5f

// chunked activation layout: plane kc = c>>5, elem = ((kc*SPATIAL)+s)*32 + (c&31)

typedef __attribute__((ext_vector_type(8))) short short8;
typedef __attribute__((ext_vector_type(4))) float f32x4;

#define MFMA(a,b,c) __builtin_amdgcn_mfma_f32_16x16x32_bf16((a),(b),(c),0,0,0)

__device__ __forceinline__ ushort f2bf(float f){
    union { float f; unsigned u; } v; v.f = f;
    return (ushort)((v.u + 0x7FFFu + ((v.u >> 16) & 1u)) >> 16);  // RNE
}
__device__ __forceinline__ float gelu_f(float v){
    return 0.5f*v*(1.0f + erff(v*0.70710678118654752f));
}

__device__ __forceinline__ void block_reduce2_atomic8(float v0, float v1,
                                                      float* d0, float* d1){
    #pragma unroll
    for (int off = 32; off > 0; off >>= 1){
        v0 += __shfl_down(v0, off);
        v1 += __shfl_down(v1, off);
    }
    __shared__ float s0[8], s1[8];
    int wv = threadIdx.x >> 6, lane = threadIdx.x & 63;
    if (lane == 0){ s0[wv] = v0; s1[wv] = v1; }
    __syncthreads();
    if (threadIdx.x == 0){
        float a = 0.f, b = 0.f;
        #pragma unroll
        for (int i = 0; i < 8; ++i){ a += s0[i]; b += s1[i]; }
        atomicAdd(d0, a);
        atomicAdd(d1, b);
    }
}

// W[o][c] fp32 -> bf16 padded row-major [160][CPAD]
__global__ __launch_bounds__(256)
void prep_weights(const float* __restrict__ w0, const float* __restrict__ w1,
                  const float* __restrict__ w2, const float* __restrict__ w3,
                  ushort* __restrict__ o0, ushort* __restrict__ o1,
                  ushort* __restrict__ o2, ushort* __restrict__ o3){
    const float* src[4] = {w0,w1,w2,w3};
    ushort*      dst[4] = {o0,o1,o2,o3};
    int m = blockIdx.y;
    int e = blockIdx.x*256 + threadIdx.x;
    if (e >= WELEM) return;
    int o = e / CPAD, c = e - o*CPAD;
    dst[m][e] = (c < CH) ? f2bf(src[m][o*CH + c]) : (ushort)0;
}

// conv1: o-split x2 (80 outputs/block). A = x (direct fp32 loads + cvt), B = W slice.
// grid 864 = 8 xcd * 54 sp * 2 osl. 1 barrier. VGPR<=64 (launch_bounds 512,8).
__global__ __launch_bounds__(512, 8)
void conv1_mfma(const float* __restrict__ x, const ushort* __restrict__ wp,
                const float* __restrict__ bias, float* __restrict__ h1c,
                float* __restrict__ stats){
    __shared__ ushort WL[80][CPAD];                   // 26.9 KB
    int t = threadIdx.x;
    int xcd = blockIdx.x & 7, r = blockIdx.x >> 3;    // r < 108
    int osl = r & 1, sl = r >> 1;                     // o-siblings adjacent on XCD
    int s_base = (xcd*54 + sl)*256;
    int o_base = osl*80;

    const short8* ws = (const short8*)(wp + o_base*CPAD);
    for (int k = t; k < 80*CPAD/8; k += 512) ((short8*)WL)[k] = ws[k];
    __syncthreads();

    int l = t & 63, wv = t >> 6, ln = l & 15, lg = l >> 4;
    float lsum = 0.f, lsq = 0.f;

    #pragma unroll 1
    for (int ms = 0; ms < 2; ++ms){
        int sA = s_base + wv*32 + ms*16 + ln;

        short8 a[5];
        #pragma unroll
        for (int ks = 0; ks < 5; ++ks){
            const float* xp = x + (ks*32 + lg*8)*SPATIAL + sA;
            #pragma unroll
            for (int i = 0; i < 8; ++i)
                a[ks][i] = (short)f2bf(xp[i*SPATIAL]);
        }

        f32x4 acc[5];
        #pragma unroll
        for (int nt = 0; nt < 5; ++nt) acc[nt] = (f32x4)0.f;

        #pragma unroll
        for (int ks = 0; ks < 5; ++ks)
            #pragma unroll
            for (int nt = 0; nt < 5; ++nt){
                short8 b = *(const short8*)&WL[nt*16 + ln][ks*32 + lg*8];
                acc[nt] = MFMA(a[ks], b, acc[nt]);
            }

        #pragma unroll
        for (int nt = 0; nt < 5; ++nt){
            int oc = o_base + nt*16 + ln;
            float bv = bias[oc];
            int kc = oc >> 5, ci = oc & 31;
            #pragma unroll
            for (int q = 0; q < 4; ++q){
                int srow = s_base + wv*32 + ms*16 + lg*4 + q;
                float val = acc[nt][q] + bv;
                h1c[(kc*SPATIAL + srow)*32 + ci] = val;
                lsum += val; lsq += val*val;
            }
        }
    }
    block_reduce2_atomic8(lsum, lsq, stats, stats+1);
}

// GN1 affine + exact GELU: chunked fp32 -> chunked bf16
__global__ __launch_bounds__(256)
void gn_gelu(const float* __restrict__ h, const float* __restrict__ g,
             const float* __restrict__ be, const float* __restrict__ stats,
             ushort* __restrict__ out){
    const float inv_n = 1.0f/(float)NTOT;
    float mu  = stats[0]*inv_n;
    float var = stats[1]*inv_n - mu*mu;
    float rs  = rsqrtf(var + EPSV);
    int nvec = NTOT/4;
    for (int i = blockIdx.x*256 + threadIdx.x; i < nvec; i += gridDim.x*256){
        int kc = (i >> 3) / SPATIAL;
        int c0 = kc*32 + (i & 7)*4;
        float4 gv = *(const float4*)&g[c0];
        float4 bv = *(const float4*)&be[c0];
        float4 x4 = ((const float4*)h)[i];
        ushort4 o;
        o.x = f2bf(gelu_f(fmaf(x4.x, rs*gv.x, bv.x - mu*rs*gv.x)));
        o.y = f2bf(gelu_f(fmaf(x4.y, rs*gv.y, bv.y - mu*rs*gv.y)));
        o.z = f2bf(gelu_f(fmaf(x4.z, rs*gv.z, bv.z - mu*rs*gv.z)));
        o.w = f2bf(gelu_f(fmaf(x4.w, rs*gv.w, bv.w - mu*rs*gv.w)));
        ((ushort4*)out)[i] = o;
    }
}

// three axial-shifted conv1x1 + gelu + sum, GN2 stats.
// o-split x5 (32 outputs/block); all 3 branch W-slices resident in LDS (32.25 KB)
// -> exactly ONE barrier per block. VGPR<=64. grid 2160 = 8 xcd * 54 sp * 5 osl.
__global__ __launch_bounds__(512, 8)
void shift_conv3_mfma(const ushort* __restrict__ A2,
                      const ushort* __restrict__ w21p, const float* __restrict__ b21,
                      const ushort* __restrict__ w22p, const float* __restrict__ b22,
                      const ushort* __restrict__ w23p, const float* __restrict__ b23,
                      ushort* __restrict__ h2c, float* __restrict__ stats){
    __shared__ ushort WL[3][32][CPAD];                // 32.25 KB
    int t = threadIdx.x;
    int xcd = blockIdx.x & 7, r = blockIdx.x >> 3;    // r < 270
    int osl = r % 5, sl = r / 5;                      // o-siblings adjacent on XCD
    int s_base = (xcd*54 + sl)*256;
    int o_base = osl*32;

    short8* wl8 = (short8*)WL;
    const short8* w1s = (const short8*)(w21p + o_base*CPAD);
    const short8* w2s = (const short8*)(w22p + o_base*CPAD);
    const short8* w3s = (const short8*)(w23p + o_base*CPAD);
    for (int k = t; k < 672; k += 512) wl8[k]        = w1s[k];
    for (int k = t; k < 672; k += 512) wl8[672 + k]  = w2s[k];
    for (int k = t; k < 672; k += 512) wl8[1344 + k] = w3s[k];
    __syncthreads();

    int l = t & 63, wv = t >> 6, ln = l & 15, lg = l >> 4;
    float lsum = 0.f, lsq = 0.f;

    #pragma unroll 1
    for (int ms = 0; ms < 2; ++ms){
        int srow = s_base + wv*32 + ms*16 + ln;
        int d   = srow / 2304;
        int rem = srow - d*2304;
        int hh  = rem / 48;
        int ww  = rem - hh*48;

        f32x4 sum[2];
        sum[0] = (f32x4)0.f; sum[1] = (f32x4)0.f;

        #pragma unroll 1
        for (int br = 0; br < 3; ++br){
            const float* bb = (br == 0) ? b21 : (br == 1) ? b22 : b23;
            int AS  = (br == 0) ? 2304 : (br == 1) ? 48 : 1;
            int crd = (br == 0) ? d    : (br == 1) ? hh : ww;

            short8 a[5];
            #pragma unroll
            for (int ks = 0; ks < 5; ++ks){
                int sh = ks - 2;
                bool ok = ((unsigned)(crd - sh) < 48u);
                const short8* ap = (const short8*)
                    &A2[(ks*SPATIAL + srow - sh*AS)*32 + lg*8];
                short8 av = (short8)0;
                if (ok) av = *ap;
                a[ks] = av;
            }

            f32x4 acc[2];
            acc[0] = (f32x4)0.f; acc[1] = (f32x4)0.f;

            #pragma unroll
            for (int ks = 0; ks < 5; ++ks)
                #pragma unroll
                for (int nt = 0; nt < 2; ++nt){
                    short8 b = *(const short8*)&WL[br][nt*16 + ln][ks*32 + lg*8];
                    acc[nt] = MFMA(a[ks], b, acc[nt]);
                }

            #pragma unroll
            for (int nt = 0; nt < 2; ++nt){
                float bv = bb[o_base + nt*16 + ln];
                #pragma unroll
                for (int q = 0; q < 4; ++q)
                    sum[nt][q] += gelu_f(acc[nt][q] + bv);
            }
        }

        #pragma unroll
        for (int nt = 0; nt < 2; ++nt){
            int oc = o_base + nt*16 + ln;
            int kc = oc >> 5, ci = oc & 31;
            #pragma unroll
            for (int q = 0; q < 4; ++q){
                int sr = s_base + wv*32 + ms*16 + lg*4 + q;
                float val = sum[nt][q];
                h2c[(kc*SPATIAL + sr)*32 + ci] = f2bf(val);
                lsum += val; lsq += val*val;
            }
        }
    }
    block_reduce2_atomic8(lsum, lsq, stats+2, stats+3);
}

// fold GN2 affine into w3/b3: w3p[o][c] = w3[o][c]*a[c] (bf16 padded), b3p = b3 + w3·d
__global__ void fold_conv3(const float* __restrict__ w3, const float* __restrict__ b3,
                           const float* __restrict__ g2, const float* __restrict__ be2,
                           const float* __restrict__ stats,
                           ushort* __restrict__ w3p, float* __restrict__ b3p){
    __shared__ float a_sh[CH], d_sh[CH];
    const float inv_n = 1.0f/(float)NTOT;
    float mu  = stats[2]*inv_n;
    float var = stats[3]*inv_n - mu*mu;
    float rs  = rsqrtf(var + EPSV);
    for (int c = threadIdx.x; c < CH; c += blockDim.x){
        float a = rs*g2[c];
        a_sh[c] = a;
        d_sh[c] = be2[c] - mu*a;
    }
    __syncthreads();
    for (int e = threadIdx.x; e < WELEM; e += blockDim.x){
        int o = e / CPAD, c = e - o*CPAD;
        w3p[e] = (c < CH) ? f2bf(w3[o*CH + c]*a_sh[c]) : (ushort)0;
    }
    for (int o = threadIdx.x; o < CH; o += blockDim.x){
        float acc = b3[o];
        for (int c = 0; c < CH; ++c) acc += w3[o*CH + c]*d_sh[c];
        b3p[o] = acc;
    }
}

// conv3: o-split x5. A = W slice (M=o, 32 rows), B = X chunked. out fp32 [C][S].
__global__ __launch_bounds__(512, 8)
void conv3_mfma(const ushort* __restrict__ Xc, const ushort* __restrict__ wp,
                const float* __restrict__ bias, float* __restrict__ out){
    __shared__ ushort WL[32][CPAD];                   // 10.75 KB
    int t = threadIdx.x;
    int xcd = blockIdx.x & 7, r = blockIdx.x >> 3;    // r < 270
    int osl = r % 5, sl = r / 5;
    int s_base = (xcd*54 + sl)*256;
    int o_base = osl*32;

    const short8* ws = (const short8*)(wp + o_base*CPAD);
    for (int k = t; k < 672; k += 512) ((short8*)WL)[k] = ws[k];
    __syncthreads();

    int l = t & 63, wv = t >> 6, ln = l & 15, lg = l >> 4;
    int sB0 = s_base + wv*32 + ln;

    f32x4 acc[2][2];
    acc[0][0] = (f32x4)0.f; acc[0][1] = (f32x4)0.f;
    acc[1][0] = (f32x4)0.f; acc[1][1] = (f32x4)0.f;

    #pragma unroll
    for (int ks = 0; ks < 5; ++ks){
        short8 b[2];
        #pragma unroll
        for (int ns = 0; ns < 2; ++ns)
            b[ns] = *(const short8*)&Xc[(ks*SPATIAL + sB0 + ns*16)*32 + lg*8];
        #pragma unroll
        for (int mt = 0; mt < 2; ++mt){
            short8 a = *(const short8*)&WL[mt*16 + ln][ks*32 + lg*8];
            acc[mt][0] = MFMA(a, b[0], acc[mt][0]);
            acc[mt][1] = MFMA(a, b[1], acc[mt][1]);
        }
    }

    #pragma unroll
    for (int mt = 0; mt < 2; ++mt)
        #pragma unroll
        for (int q = 0; q < 4; ++q){
            int o = o_base + mt*16 + lg*4 + q;
            float bv = bias[o];
            #pragma unroll
            for (int ns = 0; ns < 2; ++ns)
                out[o*SPATIAL + sB0 + ns*16] = acc[mt][ns][q] + bv;
        }
}

extern "C" void kernel_launch(void* const* d_in, const int* in_sizes, int n_in,
                              void* d_out, int out_size, void* d_ws, size_t ws_size,
                              hipStream_t stream){
    const float* x   = (const float*)d_in[0];
    const float* w1  = (const float*)d_in[1];
    const float* b1  = (const float*)d_in[2];
    const float* g1  = (const float*)d_in[3];
    const float* be1 = (const float*)d_in[4];
    const float* w21 = (const float*)d_in[5];
    const float* b21 = (const float*)d_in[6];
    const float* w22 = (const float*)d_in[7];
    const float* b22 = (const float*)d_in[8];
    const float* w23 = (const float*)d_in[9];
    const float* b23 = (const float*)d_in[10];
    const float* g2  = (const float*)d_in[11];
    const float* be2 = (const float*)d_in[12];
    const float* w3  = (const float*)d_in[13];
    const float* b3  = (const float*)d_in[14];

    float*  h1c   = (float*)d_ws;                 // chunked fp32 (NTOT); later h2c overlay
    ushort* A2    = (ushort*)(h1c + NTOT);        // chunked bf16 (NTOT)
    float*  stats = (float*)(A2 + NTOT);          // 4 fp32 (pad 8)
    ushort* w1p   = (ushort*)(stats + 8);
    ushort* w21p  = w1p  + WELEM;
    ushort* w22p  = w21p + WELEM;
    ushort* w23p  = w22p + WELEM;
    ushort* w3p   = w23p + WELEM;
    float*  b3p   = (float*)(w3p + WELEM);
    ushort* h2c   = (ushort*)h1c;                 // overlays dead h1c

    hipMemsetAsync(stats, 0, 4*sizeof(float), stream);

    prep_weights<<<dim3((WELEM+255)/256, 4), dim3(256), 0, stream>>>(
        w1, w21, w22, w23, w1p, w21p, w22p, w23p);
    conv1_mfma<<<dim3(864), dim3(512), 0, stream>>>(x, w1p, b1, h1c, stats);
    gn_gelu<<<dim3(2048), dim3(256), 0, stream>>>(h1c, g1, be1, stats, A2);
    shift_conv3_mfma<<<dim3(2160), dim3(512), 0, stream>>>(
        A2, w21p, b21, w22p, b22, w23p, b23, h2c, stats);
    fold_conv3<<<dim3(1), dim3(256), 0, stream>>>(w3, b3, g2, be2, stats, w3p, b3p);
    conv3_mfma<<<dim3(2160), dim3(512), 0, stream>>>(h2c, w3p, b3p, (float*)d_out);
}